// Round 9
// baseline (912.857 us; speedup 1.0000x reference)
//
#include <hip/hip_runtime.h>
#include <hip/hip_bf16.h>

// Problem sizes (fixed by reference)
#define N_NODES   100000
#define N_EDGES   640000
#define NUM_GRAPHS 128
#define NUM_FEAT  128
#define HIDDEN    16
#define NUM_CLS   10

// Bucket sort params
#define NBLK   256                 // edge chunks
#define EPB    (N_EDGES / NBLK)    // 2500 edges per chunk (exact)
#define NBUCK  256                 // dst >> 9 -> 196 used buckets
#define BSHIFT 9
#define BNODES 512                 // nodes per bucket

#define MM1_ROWS 64
#define GRID_MM1 ((N_NODES + MM1_ROWS - 1) / MM1_ROWS)   // 1563

#define G2 1024                    // mega-kernel grid: 4/CU needed, 8/CU capacity
#define POOL_CHUNK ((N_NODES + G2 - 1) / G2)             // 98
#define G1_TILES ((N_NODES + 63) / 64)                   // 1563

// ---------------- K1: mm1 || bucket hist || zero (R5-proven) -------------------
__global__ __launch_bounds__(256) void k_mm1_bcount_z(const float* __restrict__ x,
                                                      const float* __restrict__ W1,
                                                      float* __restrict__ y,
                                                      const int* __restrict__ ei,
                                                      int* __restrict__ cnt,
                                                      int* __restrict__ zarea, int nz) {
    __shared__ float sx[MM1_ROWS][132];   // aliased as bcount's histogram
    __shared__ float sw[NUM_FEAT * HIDDEN];
    const int t = threadIdx.x;

    if (blockIdx.x >= GRID_MM1 + NBLK) {
        for (int i = t; i < nz; i += 256) zarea[i] = 0;   // sums|counts|done|bar
        return;
    }
    if (blockIdx.x >= GRID_MM1) {
        int* h = (int*)&sx[0][0];
        const int b = blockIdx.x - GRID_MM1;
        h[t] = 0;
        __syncthreads();
        const int e0 = b * EPB, e1 = e0 + EPB;
        for (int e = e0 + t; e < e1; e += 256)
            atomicAdd(&h[ei[N_EDGES + e] >> BSHIFT], 1);  // LDS atomic
        __syncthreads();
        cnt[t * NBLK + b] = h[t];   // bucket-major
        return;
    }

    const int rowbase = blockIdx.x * MM1_ROWS;
    const int nrows = min(MM1_ROWS, N_NODES - rowbase);

    for (int i = t; i < NUM_FEAT * HIDDEN; i += 256) sw[i] = W1[i];
    for (int i = t; i < nrows * 32; i += 256) {
        int r = i >> 5, q = i & 31;
        float4 v = ((const float4*)(x + (size_t)(rowbase + r) * NUM_FEAT))[q];
        *(float4*)&sx[r][q * 4] = v;
    }
    __syncthreads();

    const int r  = t >> 2;
    const int c0 = (t & 3) * 4;
    if (r < nrows) {
        float4 o = {0.f, 0.f, 0.f, 0.f};
        #pragma unroll 4
        for (int k4 = 0; k4 < 32; ++k4) {
            float4 xv = *(const float4*)&sx[r][k4 * 4];
            const float* wb = &sw[(k4 * 4) * HIDDEN + c0];
            float4 w0 = *(const float4*)(wb);
            float4 w1 = *(const float4*)(wb + HIDDEN);
            float4 w2 = *(const float4*)(wb + 2 * HIDDEN);
            float4 w3 = *(const float4*)(wb + 3 * HIDDEN);
            o.x += xv.x * w0.x + xv.y * w1.x + xv.z * w2.x + xv.w * w3.x;
            o.y += xv.x * w0.y + xv.y * w1.y + xv.z * w2.y + xv.w * w3.y;
            o.z += xv.x * w0.z + xv.y * w1.z + xv.z * w2.z + xv.w * w3.z;
            o.w += xv.x * w0.w + xv.y * w1.w + xv.z * w2.w + xv.w * w3.w;
        }
        ((float4*)(y + (size_t)(rowbase + r) * HIDDEN))[t & 3] = o;
    }
}

// ---------------- software grid barrier (validated device-scope idiom) ---------
__device__ __forceinline__ void grid_bar(int* bar, int idx, int target) {
    __syncthreads();
    if (threadIdx.x == 0) {
        __threadfence();   // prior plain stores visible device-wide
        __hip_atomic_fetch_add(bar + idx, 1, __ATOMIC_RELEASE, __HIP_MEMORY_SCOPE_AGENT);
        while (__hip_atomic_load(bar + idx, __ATOMIC_ACQUIRE, __HIP_MEMORY_SCOPE_AGENT) < target)
            __builtin_amdgcn_s_sleep(2);
        __threadfence();
    }
    __syncthreads();
}

// ---------------- K2: bscan -> place -> build -> g1f -> pool -> FC -------------
struct alignas(16) SM2 {
    union {
        int scan[256];                                                        // bscan
        struct { int bb[NBUCK]; int cur[NBUCK]; } pl;                         // place
        struct { int bb[NBUCK]; int h[BNODES]; int ps[256];
                 int e2[BNODES]; int cur[BNODES]; } bu;                       // build 8KB
        float sw2[HIDDEN * HIDDEN];                                           // g1f
        struct { float ssum[NUM_GRAPHS * HIDDEN]; float scnt[NUM_GRAPHS]; } pool; // 8.5KB
    } u;
};

__global__ __launch_bounds__(256, 4) void k_mega(
    const int* __restrict__ ei, const int* __restrict__ batch,
    const float* __restrict__ b1, const float* __restrict__ W2,
    const float* __restrict__ b2,
    const float* __restrict__ Wfc, const float* __restrict__ bfc,
    float* __restrict__ out,
    const float* __restrict__ A, float* __restrict__ B,
    int* __restrict__ cnt, int* __restrict__ btot,
    unsigned* __restrict__ packed, int* __restrict__ srcidx,
    int* __restrict__ row,
    float* __restrict__ sums, float* __restrict__ counts,
    unsigned* __restrict__ done, int* __restrict__ bar)
{
    __shared__ SM2 sm;
    __shared__ unsigned sdone;
    const int t = threadIdx.x;
    const int bid = blockIdx.x;

    // ===== P0: bscan — per-bucket exclusive scan of 256 chunk-counts ==========
    for (int k = bid; k < NBUCK; k += G2) {
        int v = cnt[k * NBLK + t];
        sm.u.scan[t] = v;
        __syncthreads();
        for (int off = 1; off < 256; off <<= 1) {
            int add = (t >= off) ? sm.u.scan[t - off] : 0;
            __syncthreads();
            sm.u.scan[t] += add;
            __syncthreads();
        }
        cnt[k * NBLK + t] = sm.u.scan[t] - v;
        if (t == 255) btot[k] = sm.u.scan[t];
        __syncthreads();
    }
    grid_bar(bar, 0, G2);

    // ===== P1: place edges into bucket regions (LDS cursors) ==================
    for (int c = bid; c < NBLK; c += G2) {
        int v = btot[t];
        sm.u.pl.bb[t] = v;
        __syncthreads();
        for (int off = 1; off < NBUCK; off <<= 1) {
            int add = (t >= off) ? sm.u.pl.bb[t - off] : 0;
            __syncthreads();
            sm.u.pl.bb[t] += add;
            __syncthreads();
        }
        sm.u.pl.cur[t] = (sm.u.pl.bb[t] - v) + cnt[t * NBLK + c];
        __syncthreads();
        const int e0 = c * EPB, e1 = e0 + EPB;
        for (int e = e0 + t; e < e1; e += 256) {
            int srcv = ei[e];
            int dstv = ei[N_EDGES + e];
            int kk = dstv >> BSHIFT;
            int slot = atomicAdd(&sm.u.pl.cur[kk], 1);                // LDS
            packed[slot] = ((unsigned)(dstv & (BNODES - 1)) << 17) | (unsigned)srcv;
        }
        __syncthreads();
    }
    grid_bar(bar, 1, G2);

    // ===== P2: per-bucket row[] + srcidx[] ====================================
    for (int k = bid; k < NBUCK; k += G2) {
        int v = btot[t];
        sm.u.bu.bb[t] = v;
        __syncthreads();
        for (int off = 1; off < NBUCK; off <<= 1) {
            int add = (t >= off) ? sm.u.bu.bb[t - off] : 0;
            __syncthreads();
            sm.u.bu.bb[t] += add;
            __syncthreads();
        }
        const int s1 = sm.u.bu.bb[k];
        const int s0 = (k == 0) ? 0 : sm.u.bu.bb[k - 1];
        sm.u.bu.h[t] = 0; sm.u.bu.h[t + 256] = 0;
        __syncthreads();
        for (int i = s0 + t; i < s1; i += 256)
            atomicAdd(&sm.u.bu.h[packed[i] >> 17], 1);
        __syncthreads();
        int pv = sm.u.bu.h[2 * t] + sm.u.bu.h[2 * t + 1];
        sm.u.bu.ps[t] = pv;
        __syncthreads();
        for (int off = 1; off < 256; off <<= 1) {
            int add = (t >= off) ? sm.u.bu.ps[t - off] : 0;
            __syncthreads();
            sm.u.bu.ps[t] += add;
            __syncthreads();
        }
        int ex = sm.u.bu.ps[t] - pv;
        sm.u.bu.e2[2 * t] = ex;
        sm.u.bu.e2[2 * t + 1] = ex + sm.u.bu.h[2 * t];
        sm.u.bu.cur[2 * t] = ex;
        sm.u.bu.cur[2 * t + 1] = ex + sm.u.bu.h[2 * t];
        __syncthreads();
        #pragma unroll
        for (int jj = 0; jj < 2; ++jj) {
            int j = t + jj * 256;
            int node = (k << BSHIFT) + j;
            if (node <= N_NODES) row[node] = s0 + sm.u.bu.e2[j];  // row[N] sentinel
        }
        __syncthreads();
        for (int i = s0 + t; i < s1; i += 256) {
            unsigned p = packed[i];
            int dl = p >> 17;
            int slot = atomicAdd(&sm.u.bu.cur[dl], 1);            // LDS
            srcidx[s0 + slot] = (int)(p & 0x1FFFFu);
        }
        __syncthreads();
    }
    grid_bar(bar, 2, G2);

    // ===== P3: B[n] = relu(A[n] + sum A[src] + b1) @ W2 =======================
    if (t < HIDDEN * HIDDEN) sm.u.sw2[t] = W2[t];
    __syncthreads();
    for (int tile = bid; tile < G1_TILES; tile += G2) {
        const int n = tile * 64 + (t >> 2);
        const int p = t & 3;
        if (n < N_NODES) {
            const int r0 = row[n];
            const int d  = row[n + 1] - r0;
            float4 acc = ((const float4*)(A + (size_t)n * HIDDEN))[p];
            for (int i = 0; i < d; ++i) {
                int s = srcidx[r0 + i];
                float4 v = ((const float4*)(A + (size_t)s * HIDDEN))[p];
                acc.x += v.x; acc.y += v.y; acc.z += v.z; acc.w += v.w;
            }
            const float4 bv = ((const float4*)b1)[p];
            acc.x = fmaxf(acc.x + bv.x, 0.f);
            acc.y = fmaxf(acc.y + bv.y, 0.f);
            acc.z = fmaxf(acc.z + bv.z, 0.f);
            acc.w = fmaxf(acc.w + bv.w, 0.f);
            const int lane = t & 63;
            const int qbase = lane & ~3;
            const int c0 = p * 4;
            float4 o = {0.f, 0.f, 0.f, 0.f};
            #pragma unroll
            for (int q = 0; q < 4; ++q) {
                float hx = __shfl(acc.x, qbase + q, 64);
                float hy = __shfl(acc.y, qbase + q, 64);
                float hz = __shfl(acc.z, qbase + q, 64);
                float hw = __shfl(acc.w, qbase + q, 64);
                const float* wb = &sm.u.sw2[(q * 4) * HIDDEN + c0];
                float4 w0 = *(const float4*)(wb);
                float4 w1 = *(const float4*)(wb + HIDDEN);
                float4 w2 = *(const float4*)(wb + 2 * HIDDEN);
                float4 w3 = *(const float4*)(wb + 3 * HIDDEN);
                o.x += hx * w0.x + hy * w1.x + hz * w2.x + hw * w3.x;
                o.y += hx * w0.y + hy * w1.y + hz * w2.y + hw * w3.y;
                o.z += hx * w0.z + hy * w1.z + hz * w2.z + hw * w3.z;
                o.w += hx * w0.w + hy * w1.w + hz * w2.w + hw * w3.w;
            }
            ((float4*)(B + (size_t)n * HIDDEN))[p] = o;
        }
    }
    grid_bar(bar, 3, G2);

    // ===== P4: pool(relu(B[n] + sum B[src] + b2)) -> sums/counts ==============
    for (int i = t; i < NUM_GRAPHS * HIDDEN; i += 256) sm.u.pool.ssum[i] = 0.f;
    if (t < NUM_GRAPHS) sm.u.pool.scnt[t] = 0.f;
    __syncthreads();
    {
        const int n0 = bid * POOL_CHUNK;
        const int n1 = min(n0 + POOL_CHUNK, N_NODES);
        const int lane = t & 63;
        const int p = t & 3;
        const float4 bv = ((const float4*)b2)[p];
        for (int nb = n0; nb < n1; nb += 64) {
            int n = nb + (t >> 2);
            bool active = (n < n1);
            int nc = active ? n : (n1 - 1);
            int g = batch[nc];
            float4 h = {0.f, 0.f, 0.f, 0.f};
            if (active) {
                int r0 = row[n];
                int d  = row[n + 1] - r0;
                h = ((const float4*)(B + (size_t)n * HIDDEN))[p];
                for (int i = 0; i < d; ++i) {
                    int s = srcidx[r0 + i];
                    float4 v = ((const float4*)(B + (size_t)s * HIDDEN))[p];
                    h.x += v.x; h.y += v.y; h.z += v.z; h.w += v.w;
                }
                h.x = fmaxf(h.x + bv.x, 0.f);
                h.y = fmaxf(h.y + bv.y, 0.f);
                h.z = fmaxf(h.z + bv.z, 0.f);
                h.w = fmaxf(h.w + bv.w, 0.f);
            }
            int gf = __builtin_amdgcn_readfirstlane(g);
            bool uniform = (__ballot(g == gf) == ~0ull);
            if (uniform) {
                #pragma unroll
                for (int m = 4; m <= 32; m <<= 1) {
                    h.x += __shfl_xor(h.x, m, 64);
                    h.y += __shfl_xor(h.y, m, 64);
                    h.z += __shfl_xor(h.z, m, 64);
                    h.w += __shfl_xor(h.w, m, 64);
                }
                if (lane < 4) {
                    float* sp = &sm.u.pool.ssum[gf * HIDDEN + p * 4];
                    atomicAdd(sp + 0, h.x);
                    atomicAdd(sp + 1, h.y);
                    atomicAdd(sp + 2, h.z);
                    atomicAdd(sp + 3, h.w);
                }
                if (lane == 0) {
                    int wfirst = nb + ((t >> 6) << 4);
                    int cnt2 = min(16, n1 - wfirst);
                    if (cnt2 > 0) atomicAdd(&sm.u.pool.scnt[gf], (float)cnt2);
                }
            } else if (active) {
                float* sp = &sm.u.pool.ssum[g * HIDDEN + p * 4];
                atomicAdd(sp + 0, h.x);
                atomicAdd(sp + 1, h.y);
                atomicAdd(sp + 2, h.z);
                atomicAdd(sp + 3, h.w);
                if (p == 0) atomicAdd(&sm.u.pool.scnt[g], 1.f);
            }
        }
    }
    __syncthreads();
    for (int i = t; i < NUM_GRAPHS * HIDDEN; i += 256) {
        float v = sm.u.pool.ssum[i];
        if (v != 0.f) atomicAdd(&sums[i], v);
    }
    if (t < NUM_GRAPHS) {
        float v = sm.u.pool.scnt[t];
        if (v != 0.f) atomicAdd(&counts[t], v);
    }
    __syncthreads();   // drain this block's flush before signaling
    if (t == 0) sdone = atomicAdd(done, 1u);
    __syncthreads();

    // ===== P5: FC head — last-arriver block (validated R7 pattern) ============
    if (sdone == G2 - 1) {
        __threadfence();
        for (int i = t; i < NUM_GRAPHS * NUM_CLS; i += 256) {
            int g = i / NUM_CLS, c = i % NUM_CLS;
            float inv = 1.0f / fmaxf(counts[g], 1.0f);
            float acc = bfc[c];
            #pragma unroll
            for (int kk = 0; kk < HIDDEN; ++kk)
                acc += (sums[g * HIDDEN + kk] * inv) * Wfc[kk * NUM_CLS + c];
            out[i] = acc;
        }
    }
}

extern "C" void kernel_launch(void* const* d_in, const int* in_sizes, int n_in,
                              void* d_out, int out_size, void* d_ws, size_t ws_size,
                              hipStream_t stream) {
    const float* x    = (const float*)d_in[0];
    const int*   ei   = (const int*)d_in[1];   // [2, E] (src row then dst row)
    const int*   batch= (const int*)d_in[2];
    const float* W1   = (const float*)d_in[3];
    const float* b1   = (const float*)d_in[4];
    const float* W2   = (const float*)d_in[5];
    const float* b2   = (const float*)d_in[6];
    const float* Wfc  = (const float*)d_in[7];
    const float* bfc  = (const float*)d_in[8];
    float* out = (float*)d_out;

    const size_t NB = (size_t)N_NODES * HIDDEN * sizeof(float);   // 6.4 MB
    char* ws = (char*)d_ws;
    size_t off = 0;
    float* A = (float*)(ws + off); off += NB;
    float* B = (float*)(ws + off); off += NB;
    // zero-area (contiguous): sums | counts | done | bar
    float*    sums   = (float*)(ws + off);    off += (size_t)NUM_GRAPHS * HIDDEN * sizeof(float);
    float*    counts = (float*)(ws + off);    off += (size_t)NUM_GRAPHS * sizeof(float);
    unsigned* done   = (unsigned*)(ws + off); off += 16;
    int*      bar    = (int*)(ws + off);      off += 8 * sizeof(int);
    const int nz = NUM_GRAPHS * HIDDEN + NUM_GRAPHS + 4 + 8;
    int* row  = (int*)(ws + off); off += (size_t)(N_NODES + 4) * sizeof(int);
    int* cnt  = (int*)(ws + off); off += (size_t)NBUCK * NBLK * sizeof(int);
    int* btot = (int*)(ws + off); off += (size_t)NBUCK * sizeof(int);
    off = (off + 15) & ~(size_t)15;
    int* srcidx = (int*)(ws + off); off += (size_t)N_EDGES * sizeof(int);
    // packed edge words alias B: written in P1, read in P2, B overwritten in P3.
    unsigned* packed = (unsigned*)B;

    // K1: mm1 || bucket histogram || zeroing (one launch; R5-proven)
    k_mm1_bcount_z<<<GRID_MM1 + NBLK + 1, 256, 0, stream>>>(x, W1, A, ei, cnt,
                                                            (int*)sums, nz);
    // K2: everything else, chained with software grid barriers
    k_mega<<<G2, 256, 0, stream>>>(ei, batch, b1, W2, b2, Wfc, bfc, out,
                                   A, B, cnt, btot, packed, srcidx, row,
                                   sums, counts, done, bar);
}

// Round 10
// 94.239 us; speedup vs baseline: 9.6866x; 9.6866x over previous
//
#include <hip/hip_runtime.h>
#include <hip/hip_bf16.h>

// Problem sizes (fixed by reference)
#define N_NODES   100000
#define N_EDGES   640000
#define NUM_GRAPHS 128
#define NUM_FEAT  128
#define HIDDEN    16
#define NUM_CLS   10

// Bucket sort params
#define NBLK   256                 // edge chunks
#define EPB    (N_EDGES / NBLK)    // 2500 edges per chunk (exact)
#define NBUCK  256                 // dst >> 9 -> 196 used buckets
#define BSHIFT 9
#define BNODES 512                 // nodes per bucket
#define CAP    4096                // fixed region per bucket (max bucket ~3550)

#define MM1_ROWS 64
#define GRID_MM1 ((N_NODES + MM1_ROWS - 1) / MM1_ROWS)   // 1563

// ---------------- K1: mm1 || bucket hist || zero (R5-proven overlap) -----------
__global__ __launch_bounds__(256) void k_mm1_bcount_z(const float* __restrict__ x,
                                                      const float* __restrict__ W1,
                                                      float* __restrict__ y,
                                                      const int* __restrict__ ei,
                                                      int* __restrict__ cnt,
                                                      int* __restrict__ zarea, int nz) {
    __shared__ float sx[MM1_ROWS][132];   // aliased as bcount's histogram
    __shared__ float sw[NUM_FEAT * HIDDEN];
    const int t = threadIdx.x;

    if (blockIdx.x >= GRID_MM1 + NBLK) {
        for (int i = t; i < nz; i += 256) zarea[i] = 0;   // gcur|sums|counts|done
        return;
    }
    if (blockIdx.x >= GRID_MM1) {
        // ---- bucket histogram role (LDS atomics only) ----
        int* h = (int*)&sx[0][0];
        const int b = blockIdx.x - GRID_MM1;
        h[t] = 0;
        __syncthreads();
        const int e0 = b * EPB, e1 = e0 + EPB;
        for (int e = e0 + t; e < e1; e += 256)
            atomicAdd(&h[ei[N_EDGES + e] >> BSHIFT], 1);
        __syncthreads();
        cnt[b * NBUCK + t] = h[t];   // chunk-major: coalesced read in k_place2
        return;
    }

    // ---- mm1 role ----
    const int rowbase = blockIdx.x * MM1_ROWS;
    const int nrows = min(MM1_ROWS, N_NODES - rowbase);

    for (int i = t; i < NUM_FEAT * HIDDEN; i += 256) sw[i] = W1[i];
    for (int i = t; i < nrows * 32; i += 256) {
        int r = i >> 5, q = i & 31;
        float4 v = ((const float4*)(x + (size_t)(rowbase + r) * NUM_FEAT))[q];
        *(float4*)&sx[r][q * 4] = v;
    }
    __syncthreads();

    const int r  = t >> 2;
    const int c0 = (t & 3) * 4;
    if (r < nrows) {
        float4 o = {0.f, 0.f, 0.f, 0.f};
        #pragma unroll 4
        for (int k4 = 0; k4 < 32; ++k4) {
            float4 xv = *(const float4*)&sx[r][k4 * 4];
            const float* wb = &sw[(k4 * 4) * HIDDEN + c0];
            float4 w0 = *(const float4*)(wb);
            float4 w1 = *(const float4*)(wb + HIDDEN);
            float4 w2 = *(const float4*)(wb + 2 * HIDDEN);
            float4 w3 = *(const float4*)(wb + 3 * HIDDEN);
            o.x += xv.x * w0.x + xv.y * w1.x + xv.z * w2.x + xv.w * w3.x;
            o.y += xv.x * w0.y + xv.y * w1.y + xv.z * w2.y + xv.w * w3.y;
            o.z += xv.x * w0.z + xv.y * w1.z + xv.z * w2.z + xv.w * w3.z;
            o.w += xv.x * w0.w + xv.y * w1.w + xv.z * w2.w + xv.w * w3.w;
        }
        ((float4*)(y + (size_t)(rowbase + r) * HIDDEN))[t & 3] = o;
    }
}

// ---------------- K2: capacity-alloc + place (hist precomputed in K1) ----------
// Block b: read its chunk's 256 hist values (coalesced 1KB); thread t allocates
// a sub-region of bucket t's CAP region via ONE global atomicAdd; place edges
// via LDS cursors. (R7-proven place2, minus the in-kernel hist.)
__global__ __launch_bounds__(256) void k_place2(const int* __restrict__ ei,
                                                const int* __restrict__ cnt,
                                                int* __restrict__ gcur,
                                                unsigned* __restrict__ packed) {
    __shared__ int cur[NBUCK];
    const int t = threadIdx.x, b = blockIdx.x;
    int h = cnt[b * NBUCK + t];
    int base = (h > 0) ? atomicAdd(&gcur[t], h) : 0;      // 1 global atomic/bucket
    cur[t] = t * CAP + base;
    __syncthreads();
    const int e0 = b * EPB, e1 = e0 + EPB;
    for (int e = e0 + t; e < e1; e += 256) {
        int srcv = ei[e];
        int dstv = ei[N_EDGES + e];
        int k = dstv >> BSHIFT;
        int slot = atomicAdd(&cur[k], 1);                 // LDS atomic
        packed[slot] = ((unsigned)(dstv & (BNODES - 1)) << 17) | (unsigned)srcv;
    }
}

// ---------------- K3: per-bucket row/deg + srcidx (R7-proven) ------------------
__global__ __launch_bounds__(256) void k_build2(const unsigned* __restrict__ packed,
                                                const int* __restrict__ gcur,
                                                int* __restrict__ row,
                                                int* __restrict__ deg,
                                                int* __restrict__ srcidx) {
    __shared__ int h[BNODES];
    __shared__ int ps[256];
    __shared__ int e2[BNODES];
    __shared__ int cur[BNODES];
    const int k = blockIdx.x, t = threadIdx.x;
    const int s0 = k * CAP;
    const int s1 = s0 + gcur[k];

    h[t] = 0; h[t + 256] = 0;
    __syncthreads();
    for (int i = s0 + t; i < s1; i += 256)
        atomicAdd(&h[packed[i] >> 17], 1);
    __syncthreads();
    int pv = h[2 * t] + h[2 * t + 1];
    ps[t] = pv;
    __syncthreads();
    for (int off = 1; off < 256; off <<= 1) {
        int add = (t >= off) ? ps[t - off] : 0;
        __syncthreads();
        ps[t] += add;
        __syncthreads();
    }
    int ex = ps[t] - pv;
    e2[2 * t] = ex;               e2[2 * t + 1] = ex + h[2 * t];
    cur[2 * t] = ex;              cur[2 * t + 1] = ex + h[2 * t];
    __syncthreads();
    #pragma unroll
    for (int jj = 0; jj < 2; ++jj) {
        int j = t + jj * 256;
        int node = (k << BSHIFT) + j;
        if (node < N_NODES) {
            row[node] = s0 + e2[j];
            deg[node] = h[j];
        }
    }
    __syncthreads();
    for (int i = s0 + t; i < s1; i += 256) {
        unsigned p = packed[i];
        int dl = p >> 17;
        int slot = atomicAdd(&cur[dl], 1);             // LDS atomic
        srcidx[s0 + slot] = (int)(p & 0x1FFFFu);
    }
}

// ---- K4 g1f: B[n] = relu(A[n] + sum A[src] + b1) @ W2  (R7-proven) ------------
__global__ __launch_bounds__(256) void k_g1f(const int* __restrict__ row,
                                             const int* __restrict__ deg,
                                             const int* __restrict__ srcidx,
                                             const float* __restrict__ A,
                                             const float* __restrict__ bias,
                                             const float* __restrict__ W2,
                                             float* __restrict__ B, int N) {
    __shared__ float sw[HIDDEN * HIDDEN];
    const int t = threadIdx.x;
    if (t < HIDDEN * HIDDEN) sw[t] = W2[t];
    __syncthreads();
    const int n = blockIdx.x * 64 + (t >> 2);
    const int p = t & 3;
    if (n >= N) return;
    const int r0 = row[n];
    const int d  = deg[n];
    float4 acc = ((const float4*)(A + (size_t)n * HIDDEN))[p];
    for (int i = 0; i < d; ++i) {
        int s = srcidx[r0 + i];
        float4 v = ((const float4*)(A + (size_t)s * HIDDEN))[p];
        acc.x += v.x; acc.y += v.y; acc.z += v.z; acc.w += v.w;
    }
    const float4 bv = ((const float4*)bias)[p];
    acc.x = fmaxf(acc.x + bv.x, 0.f);
    acc.y = fmaxf(acc.y + bv.y, 0.f);
    acc.z = fmaxf(acc.z + bv.z, 0.f);
    acc.w = fmaxf(acc.w + bv.w, 0.f);
    const int lane = t & 63;
    const int qbase = lane & ~3;
    const int c0 = p * 4;
    float4 o = {0.f, 0.f, 0.f, 0.f};
    #pragma unroll
    for (int q = 0; q < 4; ++q) {
        float hx = __shfl(acc.x, qbase + q, 64);
        float hy = __shfl(acc.y, qbase + q, 64);
        float hz = __shfl(acc.z, qbase + q, 64);
        float hw = __shfl(acc.w, qbase + q, 64);
        const float* wb = &sw[(q * 4) * HIDDEN + c0];
        float4 w0 = *(const float4*)(wb);
        float4 w1 = *(const float4*)(wb + HIDDEN);
        float4 w2 = *(const float4*)(wb + 2 * HIDDEN);
        float4 w3 = *(const float4*)(wb + 3 * HIDDEN);
        o.x += hx * w0.x + hy * w1.x + hz * w2.x + hw * w3.x;
        o.y += hx * w0.y + hy * w1.y + hz * w2.y + hw * w3.y;
        o.z += hx * w0.z + hy * w1.z + hz * w2.z + hw * w3.z;
        o.w += hx * w0.w + hy * w1.w + hz * w2.w + hw * w3.w;
    }
    ((float4*)(B + (size_t)n * HIDDEN))[p] = o;
}

// ---- K5 g2p: pool(relu(B + gather(B) + b2)); last-arriver block does FC -------
#define POOL_BLOCKS 1024
__global__ __launch_bounds__(256) void k_g2p(const int* __restrict__ row,
                                             const int* __restrict__ deg,
                                             const int* __restrict__ srcidx,
                                             const float* __restrict__ B,
                                             const float* __restrict__ bias,
                                             const int* __restrict__ batch,
                                             float* __restrict__ sums,
                                             float* __restrict__ counts,
                                             unsigned* __restrict__ done,
                                             const float* __restrict__ Wfc,
                                             const float* __restrict__ bfc,
                                             float* __restrict__ out,
                                             int N, int chunk) {
    __shared__ float ssum[NUM_GRAPHS * HIDDEN];
    __shared__ float scnt[NUM_GRAPHS];
    __shared__ unsigned sdone;
    const int t = threadIdx.x;
    for (int i = t; i < NUM_GRAPHS * HIDDEN; i += 256) ssum[i] = 0.f;
    if (t < NUM_GRAPHS) scnt[t] = 0.f;
    __syncthreads();

    const int n0 = blockIdx.x * chunk;
    const int n1 = min(n0 + chunk, N);
    const int lane = t & 63;
    const int p = t & 3;
    const float4 bv = ((const float4*)bias)[p];

    for (int nb = n0; nb < n1; nb += 64) {
        int n = nb + (t >> 2);
        bool active = (n < n1);
        int nc = active ? n : (n1 - 1);
        int g = batch[nc];
        float4 h = {0.f, 0.f, 0.f, 0.f};
        if (active) {
            int r0 = row[n];
            int d  = deg[n];
            h = ((const float4*)(B + (size_t)n * HIDDEN))[p];
            for (int i = 0; i < d; ++i) {
                int s = srcidx[r0 + i];
                float4 v = ((const float4*)(B + (size_t)s * HIDDEN))[p];
                h.x += v.x; h.y += v.y; h.z += v.z; h.w += v.w;
            }
            h.x = fmaxf(h.x + bv.x, 0.f);
            h.y = fmaxf(h.y + bv.y, 0.f);
            h.z = fmaxf(h.z + bv.z, 0.f);
            h.w = fmaxf(h.w + bv.w, 0.f);
        }
        int gf = __builtin_amdgcn_readfirstlane(g);
        bool uniform = (__ballot(g == gf) == ~0ull);
        if (uniform) {
            #pragma unroll
            for (int m = 4; m <= 32; m <<= 1) {
                h.x += __shfl_xor(h.x, m, 64);
                h.y += __shfl_xor(h.y, m, 64);
                h.z += __shfl_xor(h.z, m, 64);
                h.w += __shfl_xor(h.w, m, 64);
            }
            if (lane < 4) {
                float* sp = &ssum[gf * HIDDEN + p * 4];
                atomicAdd(sp + 0, h.x);
                atomicAdd(sp + 1, h.y);
                atomicAdd(sp + 2, h.z);
                atomicAdd(sp + 3, h.w);
            }
            if (lane == 0) {
                int wfirst = nb + ((t >> 6) << 4);
                int cnt = min(16, n1 - wfirst);
                if (cnt > 0) atomicAdd(&scnt[gf], (float)cnt);
            }
        } else if (active) {
            float* sp = &ssum[g * HIDDEN + p * 4];
            atomicAdd(sp + 0, h.x);
            atomicAdd(sp + 1, h.y);
            atomicAdd(sp + 2, h.z);
            atomicAdd(sp + 3, h.w);
            if (p == 0) atomicAdd(&scnt[g], 1.f);
        }
    }
    __syncthreads();
    // flush block partials (device-scope atomics; memory-side on gfx950)
    for (int i = t; i < NUM_GRAPHS * HIDDEN; i += 256) {
        float v = ssum[i];
        if (v != 0.f) atomicAdd(&sums[i], v);
    }
    if (t < NUM_GRAPHS) {
        float v = scnt[t];
        if (v != 0.f) atomicAdd(&counts[t], v);
    }
    __syncthreads();   // drains this block's flush before signaling done
    if (t == 0) sdone = atomicAdd(done, 1u);
    __syncthreads();
    if (sdone == POOL_BLOCKS - 1) {
        // last block: all other blocks' flushes complete -> FC head (R7-proven)
        __threadfence();
        for (int i = t; i < NUM_GRAPHS * NUM_CLS; i += 256) {
            int g = i / NUM_CLS, c = i % NUM_CLS;
            float inv = 1.0f / fmaxf(counts[g], 1.0f);
            float acc = bfc[c];
            #pragma unroll
            for (int kk = 0; kk < HIDDEN; ++kk)
                acc += (sums[g * HIDDEN + kk] * inv) * Wfc[kk * NUM_CLS + c];
            out[i] = acc;
        }
    }
}

extern "C" void kernel_launch(void* const* d_in, const int* in_sizes, int n_in,
                              void* d_out, int out_size, void* d_ws, size_t ws_size,
                              hipStream_t stream) {
    const float* x    = (const float*)d_in[0];
    const int*   ei   = (const int*)d_in[1];   // [2, E] (src row then dst row)
    const int*   batch= (const int*)d_in[2];
    const float* W1   = (const float*)d_in[3];
    const float* b1   = (const float*)d_in[4];
    const float* W2   = (const float*)d_in[5];
    const float* b2   = (const float*)d_in[6];
    const float* Wfc  = (const float*)d_in[7];
    const float* bfc  = (const float*)d_in[8];
    float* out = (float*)d_out;

    const size_t NB = (size_t)N_NODES * HIDDEN * sizeof(float);   // 6.4 MB
    char* ws = (char*)d_ws;
    size_t off = 0;
    float* A = (float*)(ws + off); off += NB;
    float* B = (float*)(ws + off); off += NB;
    // zero-area (contiguous): gcur | sums | counts | done
    int*      gcur   = (int*)(ws + off);      off += (size_t)NBUCK * sizeof(int);
    float*    sums   = (float*)(ws + off);    off += (size_t)NUM_GRAPHS * HIDDEN * sizeof(float);
    float*    counts = (float*)(ws + off);    off += (size_t)NUM_GRAPHS * sizeof(float);
    unsigned* done   = (unsigned*)(ws + off); off += 16;
    const int nz = NBUCK + NUM_GRAPHS * HIDDEN + NUM_GRAPHS + 1;
    int* row = (int*)(ws + off); off += (size_t)N_NODES * sizeof(int);
    int* deg = (int*)(ws + off); off += (size_t)N_NODES * sizeof(int);
    int* cnt = (int*)(ws + off); off += (size_t)NBLK * NBUCK * sizeof(int);
    off = (off + 15) & ~(size_t)15;
    unsigned* packed = (unsigned*)(ws + off); off += (size_t)NBUCK * CAP * sizeof(unsigned);
    int*      srcidx = (int*)(ws + off);      off += (size_t)NBUCK * CAP * sizeof(int);

    const int gridG1  = (N_NODES + 63) / 64;
    const int poolChunk = (N_NODES + POOL_BLOCKS - 1) / POOL_BLOCKS;

    // K1: mm1 || bucket histogram || zeroing (one launch; R5-proven overlap)
    k_mm1_bcount_z<<<GRID_MM1 + NBLK + 1, 256, 0, stream>>>(x, W1, A, ei, cnt,
                                                            gcur, nz);
    // K2: capacity-alloc + place (reads K1's hist; one global atomic/bucket)
    k_place2<<<NBLK, 256, 0, stream>>>(ei, cnt, gcur, packed);
    // K3: per-bucket CSR finalize (gapped srcidx, row+deg)
    k_build2<<<NBUCK, 256, 0, stream>>>(packed, gcur, row, deg, srcidx);
    // K4: layer 1+2 fused: B = relu(A + gather(A) + b1) @ W2
    k_g1f<<<gridG1, 256, 0, stream>>>(row, deg, srcidx, A, b1, W2, B, N_NODES);
    // K5: pool(relu(B + gather(B) + b2)) -> sums/counts ; last block does FC
    k_g2p<<<POOL_BLOCKS, 256, 0, stream>>>(row, deg, srcidx, B, b2, batch, sums, counts,
                                           done, Wfc, bfc, out, N_NODES, poolChunk);
}

// Round 11
// 90.115 us; speedup vs baseline: 10.1299x; 1.0458x over previous
//
#include <hip/hip_runtime.h>
#include <hip/hip_fp16.h>

// Problem sizes (fixed by reference)
#define N_NODES   100000
#define N_EDGES   640000
#define NUM_GRAPHS 128
#define NUM_FEAT  128
#define HIDDEN    16
#define NUM_CLS   10

// Bucket sort params (R5-proven pipeline)
#define NBLK   256                 // edge chunks
#define EPB    (N_EDGES / NBLK)    // 2500 edges per chunk (exact)
#define NBUCK  256                 // dst >> 9 -> 196 used buckets
#define BSHIFT 9
#define BNODES 512                 // nodes per bucket

#define MM1_ROWS 64
#define GRID_MM1 ((N_NODES + MM1_ROWS - 1) / MM1_ROWS)   // 1563

// ---- fp16 storage helpers (compute stays fp32) --------------------------------
__device__ __forceinline__ float4 ldh4(const __half* p) {
    float2 raw = *(const float2*)p;            // one 8B load
    const __half2* h = (const __half2*)&raw;
    float2 a = __half22float2(h[0]);
    float2 b = __half22float2(h[1]);
    return make_float4(a.x, a.y, b.x, b.y);
}
__device__ __forceinline__ void sth4(__half* p, float4 v) {
    float2 raw;
    ((__half2*)&raw)[0] = __floats2half2_rn(v.x, v.y);
    ((__half2*)&raw)[1] = __floats2half2_rn(v.z, v.w);
    *(float2*)p = raw;                         // one 8B store
}

// ---------------- K1: mm1 || bucket hist (R5-proven overlap) -------------------
__global__ __launch_bounds__(256) void k_mm1_bcount(const float* __restrict__ x,
                                                    const float* __restrict__ W1,
                                                    __half* __restrict__ y,
                                                    const int* __restrict__ ei,
                                                    int* __restrict__ cnt) {
    __shared__ float sx[MM1_ROWS][132];   // aliased as bcount's histogram
    __shared__ float sw[NUM_FEAT * HIDDEN];
    const int t = threadIdx.x;

    if (blockIdx.x >= GRID_MM1) {
        // ---- bucket histogram role (LDS atomics only) ----
        int* h = (int*)&sx[0][0];
        const int b = blockIdx.x - GRID_MM1;
        h[t] = 0;
        __syncthreads();
        const int e0 = b * EPB, e1 = e0 + EPB;
        for (int e = e0 + t; e < e1; e += 256)
            atomicAdd(&h[ei[N_EDGES + e] >> BSHIFT], 1);
        __syncthreads();
        cnt[t * NBLK + b] = h[t];   // bucket-major for bscan
        return;
    }

    // ---- mm1 role ----
    const int rowbase = blockIdx.x * MM1_ROWS;
    const int nrows = min(MM1_ROWS, N_NODES - rowbase);

    for (int i = t; i < NUM_FEAT * HIDDEN; i += 256) sw[i] = W1[i];
    for (int i = t; i < nrows * 32; i += 256) {
        int r = i >> 5, q = i & 31;
        float4 v = ((const float4*)(x + (size_t)(rowbase + r) * NUM_FEAT))[q];
        *(float4*)&sx[r][q * 4] = v;
    }
    __syncthreads();

    const int r  = t >> 2;
    const int c0 = (t & 3) * 4;
    if (r < nrows) {
        float4 o = {0.f, 0.f, 0.f, 0.f};
        #pragma unroll 4
        for (int k4 = 0; k4 < 32; ++k4) {
            float4 xv = *(const float4*)&sx[r][k4 * 4];
            const float* wb = &sw[(k4 * 4) * HIDDEN + c0];
            float4 w0 = *(const float4*)(wb);
            float4 w1 = *(const float4*)(wb + HIDDEN);
            float4 w2 = *(const float4*)(wb + 2 * HIDDEN);
            float4 w3 = *(const float4*)(wb + 3 * HIDDEN);
            o.x += xv.x * w0.x + xv.y * w1.x + xv.z * w2.x + xv.w * w3.x;
            o.y += xv.x * w0.y + xv.y * w1.y + xv.z * w2.y + xv.w * w3.y;
            o.z += xv.x * w0.z + xv.y * w1.z + xv.z * w2.z + xv.w * w3.z;
            o.w += xv.x * w0.w + xv.y * w1.w + xv.z * w2.w + xv.w * w3.w;
        }
        sth4(y + (size_t)(rowbase + r) * HIDDEN + (t & 3) * 4, o);
    }
}

// ---------------- K2: per-bucket exclusive scan of 256 chunk-counts ------------
// block k scans its bucket's chunk-counts; block 0 also zeroes sums/counts/done.
__global__ __launch_bounds__(256) void k_bscan(int* __restrict__ cnt,
                                               int* __restrict__ btot,
                                               int* __restrict__ zarea, int nz) {
    __shared__ int s[256];
    const int k = blockIdx.x, t = threadIdx.x;
    if (k == 0) {
        for (int i = t; i < nz; i += 256) zarea[i] = 0;   // sums|counts|done
    }
    int v = cnt[k * NBLK + t];
    s[t] = v;
    __syncthreads();
    for (int off = 1; off < 256; off <<= 1) {
        int add = (t >= off) ? s[t - off] : 0;
        __syncthreads();
        s[t] += add;
        __syncthreads();
    }
    cnt[k * NBLK + t] = s[t] - v;          // exclusive within bucket
    if (t == 255) btot[k] = s[t];
}

// ---------------- K3: place edges into bucket regions (LDS cursors) ------------
__global__ __launch_bounds__(256) void k_place(const int* __restrict__ ei,
                                               const int* __restrict__ cnt,
                                               const int* __restrict__ btot,
                                               unsigned* __restrict__ packed) {
    __shared__ int bb[NBUCK];
    __shared__ int cur[NBUCK];
    const int t = threadIdx.x, b = blockIdx.x;
    int v = btot[t];
    bb[t] = v;
    __syncthreads();
    for (int off = 1; off < NBUCK; off <<= 1) {
        int add = (t >= off) ? bb[t - off] : 0;
        __syncthreads();
        bb[t] += add;
        __syncthreads();
    }
    cur[t] = (bb[t] - v) + cnt[t * NBLK + b];   // bucket base + my chunk's offset
    __syncthreads();
    const int e0 = b * EPB, e1 = e0 + EPB;
    for (int e = e0 + t; e < e1; e += 256) {
        int srcv = ei[e];
        int dstv = ei[N_EDGES + e];
        int k = dstv >> BSHIFT;
        int slot = atomicAdd(&cur[k], 1);                 // LDS atomic
        packed[slot] = ((unsigned)(dstv & (BNODES - 1)) << 17) | (unsigned)srcv;
    }
}

// ---------------- K4: per-bucket row[] + srcidx[] (LDS hist/scan/cursor) -------
__global__ __launch_bounds__(256) void k_build(const unsigned* __restrict__ packed,
                                               const int* __restrict__ btot,
                                               int* __restrict__ row,
                                               int* __restrict__ srcidx) {
    __shared__ int bb[NBUCK];
    __shared__ int h[BNODES];
    __shared__ int ps[256];
    __shared__ int e2[BNODES];
    __shared__ int cur[BNODES];
    const int k = blockIdx.x, t = threadIdx.x;

    int v = btot[t];
    bb[t] = v;
    __syncthreads();
    for (int off = 1; off < NBUCK; off <<= 1) {
        int add = (t >= off) ? bb[t - off] : 0;
        __syncthreads();
        bb[t] += add;
        __syncthreads();
    }
    const int s1 = bb[k];
    const int s0 = s1 - btot[k];

    h[t] = 0; h[t + 256] = 0;
    __syncthreads();
    for (int i = s0 + t; i < s1; i += 256)
        atomicAdd(&h[packed[i] >> 17], 1);
    __syncthreads();
    int pv = h[2 * t] + h[2 * t + 1];
    ps[t] = pv;
    __syncthreads();
    for (int off = 1; off < 256; off <<= 1) {
        int add = (t >= off) ? ps[t - off] : 0;
        __syncthreads();
        ps[t] += add;
        __syncthreads();
    }
    int ex = ps[t] - pv;
    e2[2 * t] = ex;               e2[2 * t + 1] = ex + h[2 * t];
    cur[2 * t] = ex;              cur[2 * t + 1] = ex + h[2 * t];
    __syncthreads();
    #pragma unroll
    for (int jj = 0; jj < 2; ++jj) {
        int j = t + jj * 256;
        int node = (k << BSHIFT) + j;
        if (node <= N_NODES) row[node] = s0 + e2[j];   // row[N] sentinel = E
    }
    __syncthreads();
    for (int i = s0 + t; i < s1; i += 256) {
        unsigned p = packed[i];
        int dl = p >> 17;
        int slot = atomicAdd(&cur[dl], 1);             // LDS atomic
        srcidx[s0 + slot] = (int)(p & 0x1FFFFu);
    }
}

// ---- K5 g1f: B[n] = relu(A[n] + sum A[src] + b1) @ W2  (fp16 storage) ---------
__global__ __launch_bounds__(256) void k_g1f(const int* __restrict__ row,
                                             const int* __restrict__ srcidx,
                                             const __half* __restrict__ A,
                                             const float* __restrict__ bias,
                                             const float* __restrict__ W2,
                                             __half* __restrict__ B, int N) {
    __shared__ float sw[HIDDEN * HIDDEN];
    const int t = threadIdx.x;
    if (t < HIDDEN * HIDDEN) sw[t] = W2[t];
    __syncthreads();
    const int n = blockIdx.x * 64 + (t >> 2);
    const int p = t & 3;
    if (n >= N) return;
    const int r0 = row[n];
    const int d  = row[n + 1] - r0;
    float4 acc = ldh4(A + (size_t)n * HIDDEN + p * 4);
    for (int i = 0; i < d; ++i) {
        int s = srcidx[r0 + i];
        float4 v = ldh4(A + (size_t)s * HIDDEN + p * 4);
        acc.x += v.x; acc.y += v.y; acc.z += v.z; acc.w += v.w;
    }
    const float4 bv = ((const float4*)bias)[p];
    acc.x = fmaxf(acc.x + bv.x, 0.f);
    acc.y = fmaxf(acc.y + bv.y, 0.f);
    acc.z = fmaxf(acc.z + bv.z, 0.f);
    acc.w = fmaxf(acc.w + bv.w, 0.f);
    // h(16) @ W2 -> this thread's 4 output cols; exchange h quads via shfl
    const int lane = t & 63;
    const int qbase = lane & ~3;
    const int c0 = p * 4;
    float4 o = {0.f, 0.f, 0.f, 0.f};
    #pragma unroll
    for (int q = 0; q < 4; ++q) {
        float hx = __shfl(acc.x, qbase + q, 64);
        float hy = __shfl(acc.y, qbase + q, 64);
        float hz = __shfl(acc.z, qbase + q, 64);
        float hw = __shfl(acc.w, qbase + q, 64);
        const float* wb = &sw[(q * 4) * HIDDEN + c0];
        float4 w0 = *(const float4*)(wb);
        float4 w1 = *(const float4*)(wb + HIDDEN);
        float4 w2 = *(const float4*)(wb + 2 * HIDDEN);
        float4 w3 = *(const float4*)(wb + 3 * HIDDEN);
        o.x += hx * w0.x + hy * w1.x + hz * w2.x + hw * w3.x;
        o.y += hx * w0.y + hy * w1.y + hz * w2.y + hw * w3.y;
        o.z += hx * w0.z + hy * w1.z + hz * w2.z + hw * w3.z;
        o.w += hx * w0.w + hy * w1.w + hz * w2.w + hw * w3.w;
    }
    sth4(B + (size_t)n * HIDDEN + p * 4, o);
}

// ---- K6 g2p: pool(relu(B + gather(B) + b2)); last-arriver block does FC -------
#define POOL_BLOCKS 1024
__global__ __launch_bounds__(256) void k_g2p(const int* __restrict__ row,
                                             const int* __restrict__ srcidx,
                                             const __half* __restrict__ B,
                                             const float* __restrict__ bias,
                                             const int* __restrict__ batch,
                                             float* __restrict__ sums,
                                             float* __restrict__ counts,
                                             unsigned* __restrict__ done,
                                             const float* __restrict__ Wfc,
                                             const float* __restrict__ bfc,
                                             float* __restrict__ out,
                                             int N, int chunk) {
    __shared__ float ssum[NUM_GRAPHS * HIDDEN];
    __shared__ float scnt[NUM_GRAPHS];
    __shared__ unsigned sdone;
    const int t = threadIdx.x;
    for (int i = t; i < NUM_GRAPHS * HIDDEN; i += 256) ssum[i] = 0.f;
    if (t < NUM_GRAPHS) scnt[t] = 0.f;
    __syncthreads();

    const int n0 = blockIdx.x * chunk;
    const int n1 = min(n0 + chunk, N);
    const int lane = t & 63;
    const int p = t & 3;
    const float4 bv = ((const float4*)bias)[p];

    for (int nb = n0; nb < n1; nb += 64) {
        int n = nb + (t >> 2);
        bool active = (n < n1);
        int nc = active ? n : (n1 - 1);
        int g = batch[nc];
        float4 h = {0.f, 0.f, 0.f, 0.f};
        if (active) {
            int r0 = row[n];
            int d  = row[n + 1] - r0;
            h = ldh4(B + (size_t)n * HIDDEN + p * 4);
            for (int i = 0; i < d; ++i) {
                int s = srcidx[r0 + i];
                float4 v = ldh4(B + (size_t)s * HIDDEN + p * 4);
                h.x += v.x; h.y += v.y; h.z += v.z; h.w += v.w;
            }
            h.x = fmaxf(h.x + bv.x, 0.f);
            h.y = fmaxf(h.y + bv.y, 0.f);
            h.z = fmaxf(h.z + bv.z, 0.f);
            h.w = fmaxf(h.w + bv.w, 0.f);
        }
        int gf = __builtin_amdgcn_readfirstlane(g);
        bool uniform = (__ballot(g == gf) == ~0ull);
        if (uniform) {
            #pragma unroll
            for (int m = 4; m <= 32; m <<= 1) {
                h.x += __shfl_xor(h.x, m, 64);
                h.y += __shfl_xor(h.y, m, 64);
                h.z += __shfl_xor(h.z, m, 64);
                h.w += __shfl_xor(h.w, m, 64);
            }
            if (lane < 4) {
                float* sp = &ssum[gf * HIDDEN + p * 4];
                atomicAdd(sp + 0, h.x);
                atomicAdd(sp + 1, h.y);
                atomicAdd(sp + 2, h.z);
                atomicAdd(sp + 3, h.w);
            }
            if (lane == 0) {
                int wfirst = nb + ((t >> 6) << 4);
                int cnt = min(16, n1 - wfirst);
                if (cnt > 0) atomicAdd(&scnt[gf], (float)cnt);
            }
        } else if (active) {
            float* sp = &ssum[g * HIDDEN + p * 4];
            atomicAdd(sp + 0, h.x);
            atomicAdd(sp + 1, h.y);
            atomicAdd(sp + 2, h.z);
            atomicAdd(sp + 3, h.w);
            if (p == 0) atomicAdd(&scnt[g], 1.f);
        }
    }
    __syncthreads();
    // flush block partials (device-scope atomics; memory-side on gfx950)
    for (int i = t; i < NUM_GRAPHS * HIDDEN; i += 256) {
        float v = ssum[i];
        if (v != 0.f) atomicAdd(&sums[i], v);
    }
    if (t < NUM_GRAPHS) {
        float v = scnt[t];
        if (v != 0.f) atomicAdd(&counts[t], v);
    }
    __syncthreads();   // drain this block's flush before signaling done
    if (t == 0) sdone = atomicAdd(done, 1u);
    __syncthreads();
    if (sdone == POOL_BLOCKS - 1) {
        // last block: all other blocks' flushes complete -> FC head (validated)
        __threadfence();
        for (int i = t; i < NUM_GRAPHS * NUM_CLS; i += 256) {
            int g = i / NUM_CLS, c = i % NUM_CLS;
            float inv = 1.0f / fmaxf(counts[g], 1.0f);
            float acc = bfc[c];
            #pragma unroll
            for (int kk = 0; kk < HIDDEN; ++kk)
                acc += (sums[g * HIDDEN + kk] * inv) * Wfc[kk * NUM_CLS + c];
            out[i] = acc;
        }
    }
}

extern "C" void kernel_launch(void* const* d_in, const int* in_sizes, int n_in,
                              void* d_out, int out_size, void* d_ws, size_t ws_size,
                              hipStream_t stream) {
    const float* x    = (const float*)d_in[0];
    const int*   ei   = (const int*)d_in[1];   // [2, E] (src row then dst row)
    const int*   batch= (const int*)d_in[2];
    const float* W1   = (const float*)d_in[3];
    const float* b1   = (const float*)d_in[4];
    const float* W2   = (const float*)d_in[5];
    const float* b2   = (const float*)d_in[6];
    const float* Wfc  = (const float*)d_in[7];
    const float* bfc  = (const float*)d_in[8];
    float* out = (float*)d_out;

    const size_t NB = (size_t)N_NODES * HIDDEN * sizeof(__half);   // 3.2 MB
    char* ws = (char*)d_ws;
    size_t off = 0;
    __half* A = (__half*)(ws + off); off += NB;
    __half* B = (__half*)(ws + off); off += NB;
    // zero-area (contiguous): sums | counts | done — zeroed by k_bscan block 0
    float*    sums   = (float*)(ws + off);    off += (size_t)NUM_GRAPHS * HIDDEN * sizeof(float);
    float*    counts = (float*)(ws + off);    off += (size_t)NUM_GRAPHS * sizeof(float);
    unsigned* done   = (unsigned*)(ws + off); off += 16;
    const int nz = NUM_GRAPHS * HIDDEN + NUM_GRAPHS + 4;
    int* row  = (int*)(ws + off); off += (size_t)(N_NODES + 4) * sizeof(int);
    int* cnt  = (int*)(ws + off); off += (size_t)NBUCK * NBLK * sizeof(int);
    int* btot = (int*)(ws + off); off += (size_t)NBUCK * sizeof(int);
    off = (off + 15) & ~(size_t)15;
    int* srcidx = (int*)(ws + off); off += (size_t)N_EDGES * sizeof(int);
    // packed edge words alias B (2.56 MB <= 3.2 MB): place writes / build reads
    // strictly before k_g1f (stream-ordered) overwrites B.
    unsigned* packed = (unsigned*)B;

    const int gridG1  = (N_NODES + 63) / 64;
    const int poolChunk = (N_NODES + POOL_BLOCKS - 1) / POOL_BLOCKS;

    // K1: mm1 || bucket histogram (R5-proven overlap)
    k_mm1_bcount<<<GRID_MM1 + NBLK, 256, 0, stream>>>(x, W1, A, ei, cnt);
    // K2: per-bucket scan (+ zero sums/counts/done)
    k_bscan<<<NBUCK, 256, 0, stream>>>(cnt, btot, (int*)sums, nz);
    // K3: place edges into contiguous bucket regions
    k_place<<<NBLK, 256, 0, stream>>>(ei, cnt, btot, packed);
    // K4: per-bucket CSR finalize (contiguous srcidx, row sentinel)
    k_build<<<NBUCK, 256, 0, stream>>>(packed, btot, row, srcidx);
    // K5: layer 1+2 fused: B = relu(A + gather(A) + b1) @ W2
    k_g1f<<<gridG1, 256, 0, stream>>>(row, srcidx, A, b1, W2, B, N_NODES);
    // K6: pool(relu(B + gather(B) + b2)) -> sums/counts ; last block does FC
    k_g2p<<<POOL_BLOCKS, 256, 0, stream>>>(row, srcidx, B, b2, batch, sums, counts,
                                           done, Wfc, bfc, out, N_NODES, poolChunk);
}

// Round 12
// 89.379 us; speedup vs baseline: 10.2133x; 1.0082x over previous
//
#include <hip/hip_runtime.h>
#include <hip/hip_fp16.h>

// Problem sizes (fixed by reference)
#define N_NODES   100000
#define N_EDGES   640000
#define NUM_GRAPHS 128
#define NUM_FEAT  128
#define HIDDEN    16
#define NUM_CLS   10

// Bucket sort params (R5-proven pipeline)
#define NBLK   256                 // edge chunks
#define EPB    (N_EDGES / NBLK)    // 2500 edges per chunk (exact)
#define NBUCK  256                 // dst >> 9 -> 196 used buckets
#define BSHIFT 9
#define BNODES 512                 // nodes per bucket

#define MM1_ROWS 64
#define GRID_MM1 ((N_NODES + MM1_ROWS - 1) / MM1_ROWS)   // 1563

// ---- fp16 storage helpers (compute stays fp32) --------------------------------
__device__ __forceinline__ void sth4(__half* p, float4 v) {
    float2 raw;
    ((__half2*)&raw)[0] = __floats2half2_rn(v.x, v.y);
    ((__half2*)&raw)[1] = __floats2half2_rn(v.z, v.w);
    *(float2*)p = raw;                         // one 8B store
}
__device__ __forceinline__ void ldh8(const __half* p, float* o) {
    float4 raw = *(const float4*)p;            // one 16B load = 8 halves
    const __half2* h = (const __half2*)&raw;
    float2 a = __half22float2(h[0]);
    float2 b = __half22float2(h[1]);
    float2 c = __half22float2(h[2]);
    float2 d = __half22float2(h[3]);
    o[0] = a.x; o[1] = a.y; o[2] = b.x; o[3] = b.y;
    o[4] = c.x; o[5] = c.y; o[6] = d.x; o[7] = d.y;
}
__device__ __forceinline__ void sth8(__half* p, const float* v) {
    float4 raw;
    __half2* h = (__half2*)&raw;
    h[0] = __floats2half2_rn(v[0], v[1]);
    h[1] = __floats2half2_rn(v[2], v[3]);
    h[2] = __floats2half2_rn(v[4], v[5]);
    h[3] = __floats2half2_rn(v[6], v[7]);
    *(float4*)p = raw;                         // one 16B store
}

// ---------------- K1: mm1 || bucket hist (R5-proven overlap) -------------------
__global__ __launch_bounds__(256) void k_mm1_bcount(const float* __restrict__ x,
                                                    const float* __restrict__ W1,
                                                    __half* __restrict__ y,
                                                    const int* __restrict__ ei,
                                                    int* __restrict__ cnt) {
    __shared__ float sx[MM1_ROWS][132];   // aliased as bcount's histogram
    __shared__ float sw[NUM_FEAT * HIDDEN];
    const int t = threadIdx.x;

    if (blockIdx.x >= GRID_MM1) {
        // ---- bucket histogram role (LDS atomics only) ----
        int* h = (int*)&sx[0][0];
        const int b = blockIdx.x - GRID_MM1;
        h[t] = 0;
        __syncthreads();
        const int e0 = b * EPB, e1 = e0 + EPB;
        for (int e = e0 + t; e < e1; e += 256)
            atomicAdd(&h[ei[N_EDGES + e] >> BSHIFT], 1);
        __syncthreads();
        cnt[t * NBLK + b] = h[t];   // bucket-major for bscan
        return;
    }

    // ---- mm1 role ----
    const int rowbase = blockIdx.x * MM1_ROWS;
    const int nrows = min(MM1_ROWS, N_NODES - rowbase);

    for (int i = t; i < NUM_FEAT * HIDDEN; i += 256) sw[i] = W1[i];
    for (int i = t; i < nrows * 32; i += 256) {
        int r = i >> 5, q = i & 31;
        float4 v = ((const float4*)(x + (size_t)(rowbase + r) * NUM_FEAT))[q];
        *(float4*)&sx[r][q * 4] = v;
    }
    __syncthreads();

    const int r  = t >> 2;
    const int c0 = (t & 3) * 4;
    if (r < nrows) {
        float4 o = {0.f, 0.f, 0.f, 0.f};
        #pragma unroll 4
        for (int k4 = 0; k4 < 32; ++k4) {
            float4 xv = *(const float4*)&sx[r][k4 * 4];
            const float* wb = &sw[(k4 * 4) * HIDDEN + c0];
            float4 w0 = *(const float4*)(wb);
            float4 w1 = *(const float4*)(wb + HIDDEN);
            float4 w2 = *(const float4*)(wb + 2 * HIDDEN);
            float4 w3 = *(const float4*)(wb + 3 * HIDDEN);
            o.x += xv.x * w0.x + xv.y * w1.x + xv.z * w2.x + xv.w * w3.x;
            o.y += xv.x * w0.y + xv.y * w1.y + xv.z * w2.y + xv.w * w3.y;
            o.z += xv.x * w0.z + xv.y * w1.z + xv.z * w2.z + xv.w * w3.z;
            o.w += xv.x * w0.w + xv.y * w1.w + xv.z * w2.w + xv.w * w3.w;
        }
        sth4(y + (size_t)(rowbase + r) * HIDDEN + (t & 3) * 4, o);
    }
}

// ---------------- K2: per-bucket exclusive scan of 256 chunk-counts ------------
__global__ __launch_bounds__(256) void k_bscan(int* __restrict__ cnt,
                                               int* __restrict__ btot,
                                               int* __restrict__ zarea, int nz) {
    __shared__ int s[256];
    const int k = blockIdx.x, t = threadIdx.x;
    if (k == 0) {
        for (int i = t; i < nz; i += 256) zarea[i] = 0;   // sums|counts|done
    }
    int v = cnt[k * NBLK + t];
    s[t] = v;
    __syncthreads();
    for (int off = 1; off < 256; off <<= 1) {
        int add = (t >= off) ? s[t - off] : 0;
        __syncthreads();
        s[t] += add;
        __syncthreads();
    }
    cnt[k * NBLK + t] = s[t] - v;          // exclusive within bucket
    if (t == 255) btot[k] = s[t];
}

// ---------------- K3: place edges into bucket regions (LDS cursors) ------------
__global__ __launch_bounds__(256) void k_place(const int* __restrict__ ei,
                                               const int* __restrict__ cnt,
                                               const int* __restrict__ btot,
                                               unsigned* __restrict__ packed) {
    __shared__ int bb[NBUCK];
    __shared__ int cur[NBUCK];
    const int t = threadIdx.x, b = blockIdx.x;
    int v = btot[t];
    bb[t] = v;
    __syncthreads();
    for (int off = 1; off < NBUCK; off <<= 1) {
        int add = (t >= off) ? bb[t - off] : 0;
        __syncthreads();
        bb[t] += add;
        __syncthreads();
    }
    cur[t] = (bb[t] - v) + cnt[t * NBLK + b];   // bucket base + my chunk's offset
    __syncthreads();
    const int e0 = b * EPB, e1 = e0 + EPB;
    for (int e = e0 + t; e < e1; e += 256) {
        int srcv = ei[e];
        int dstv = ei[N_EDGES + e];
        int k = dstv >> BSHIFT;
        int slot = atomicAdd(&cur[k], 1);                 // LDS atomic
        packed[slot] = ((unsigned)(dstv & (BNODES - 1)) << 17) | (unsigned)srcv;
    }
}

// ---------------- K4: per-bucket row[] + srcidx[] (LDS hist/scan/cursor) -------
__global__ __launch_bounds__(256) void k_build(const unsigned* __restrict__ packed,
                                               const int* __restrict__ btot,
                                               int* __restrict__ row,
                                               int* __restrict__ srcidx) {
    __shared__ int bb[NBUCK];
    __shared__ int h[BNODES];
    __shared__ int ps[256];
    __shared__ int e2[BNODES];
    __shared__ int cur[BNODES];
    const int k = blockIdx.x, t = threadIdx.x;

    int v = btot[t];
    bb[t] = v;
    __syncthreads();
    for (int off = 1; off < NBUCK; off <<= 1) {
        int add = (t >= off) ? bb[t - off] : 0;
        __syncthreads();
        bb[t] += add;
        __syncthreads();
    }
    const int s1 = bb[k];
    const int s0 = s1 - btot[k];

    h[t] = 0; h[t + 256] = 0;
    __syncthreads();
    for (int i = s0 + t; i < s1; i += 256)
        atomicAdd(&h[packed[i] >> 17], 1);
    __syncthreads();
    int pv = h[2 * t] + h[2 * t + 1];
    ps[t] = pv;
    __syncthreads();
    for (int off = 1; off < 256; off <<= 1) {
        int add = (t >= off) ? ps[t - off] : 0;
        __syncthreads();
        ps[t] += add;
        __syncthreads();
    }
    int ex = ps[t] - pv;
    e2[2 * t] = ex;               e2[2 * t + 1] = ex + h[2 * t];
    cur[2 * t] = ex;              cur[2 * t + 1] = ex + h[2 * t];
    __syncthreads();
    #pragma unroll
    for (int jj = 0; jj < 2; ++jj) {
        int j = t + jj * 256;
        int node = (k << BSHIFT) + j;
        if (node <= N_NODES) row[node] = s0 + e2[j];   // row[N] sentinel = E
    }
    __syncthreads();
    for (int i = s0 + t; i < s1; i += 256) {
        unsigned p = packed[i];
        int dl = p >> 17;
        int slot = atomicAdd(&cur[dl], 1);             // LDS atomic
        srcidx[s0 + slot] = (int)(p & 0x1FFFFu);
    }
}

// ---- K5 g1f: B[n] = relu(A[n] + sum A[src] + b1) @ W2  (2 lanes/node, 16B) ----
__global__ __launch_bounds__(256) void k_g1f(const int* __restrict__ row,
                                             const int* __restrict__ srcidx,
                                             const __half* __restrict__ A,
                                             const float* __restrict__ bias,
                                             const float* __restrict__ W2,
                                             __half* __restrict__ B, int N) {
    __shared__ float sw[HIDDEN * HIDDEN];
    const int t = threadIdx.x;
    sw[t] = W2[t];      // 256 == HIDDEN*HIDDEN
    __syncthreads();
    const int n = blockIdx.x * 128 + (t >> 1);
    const int p = t & 1;
    if (n >= N) return;
    const int r0 = row[n];
    const int d  = row[n + 1] - r0;
    float acc[8];
    ldh8(A + (size_t)n * HIDDEN + p * 8, acc);
    for (int i = 0; i < d; ++i) {
        int s = srcidx[r0 + i];
        float v[8];
        ldh8(A + (size_t)s * HIDDEN + p * 8, v);
        #pragma unroll
        for (int k = 0; k < 8; ++k) acc[k] += v[k];
    }
    const float* bp = bias + p * 8;
    #pragma unroll
    for (int k = 0; k < 8; ++k) acc[k] = fmaxf(acc[k] + bp[k], 0.f);
    // reconstruct full h[16]: own 8 + partner's 8 via one-lane shfl_xor
    float hall[16];
    #pragma unroll
    for (int k = 0; k < 8; ++k) {
        float other = __shfl_xor(acc[k], 1, 64);
        hall[p * 8 + k] = acc[k];
        hall[(p ^ 1) * 8 + k] = other;
    }
    float o[8];
    #pragma unroll
    for (int cc = 0; cc < 8; ++cc) o[cc] = 0.f;
    #pragma unroll
    for (int k = 0; k < 16; ++k) {
        const float* wr = &sw[k * HIDDEN + p * 8];
        float hk = hall[k];
        #pragma unroll
        for (int cc = 0; cc < 8; ++cc) o[cc] += hk * wr[cc];
    }
    sth8(B + (size_t)n * HIDDEN + p * 8, o);
}

// ---- K6 g2p: pool(relu(B + gather(B) + b2)); last-arriver block does FC -------
#define POOL_BLOCKS 1024
__global__ __launch_bounds__(256) void k_g2p(const int* __restrict__ row,
                                             const int* __restrict__ srcidx,
                                             const __half* __restrict__ B,
                                             const float* __restrict__ bias,
                                             const int* __restrict__ batch,
                                             float* __restrict__ sums,
                                             float* __restrict__ counts,
                                             unsigned* __restrict__ done,
                                             const float* __restrict__ Wfc,
                                             const float* __restrict__ bfc,
                                             float* __restrict__ out,
                                             int N, int chunk) {
    __shared__ float ssum[NUM_GRAPHS * HIDDEN];
    __shared__ float scnt[NUM_GRAPHS];
    __shared__ unsigned sdone;
    const int t = threadIdx.x;
    for (int i = t; i < NUM_GRAPHS * HIDDEN; i += 256) ssum[i] = 0.f;
    if (t < NUM_GRAPHS) scnt[t] = 0.f;
    __syncthreads();

    const int n0 = blockIdx.x * chunk;
    const int n1 = min(n0 + chunk, N);
    const int lane = t & 63;
    const int p = t & 1;
    float bv[8];
    #pragma unroll
    for (int k = 0; k < 8; ++k) bv[k] = bias[p * 8 + k];

    for (int nb = n0; nb < n1; nb += 128) {
        int n = nb + (t >> 1);
        bool active = (n < n1);
        int nc = active ? n : (n1 - 1);
        int g = batch[nc];
        float h[8] = {0.f, 0.f, 0.f, 0.f, 0.f, 0.f, 0.f, 0.f};
        if (active) {
            int r0 = row[n];
            int d  = row[n + 1] - r0;
            ldh8(B + (size_t)n * HIDDEN + p * 8, h);
            for (int i = 0; i < d; ++i) {
                int s = srcidx[r0 + i];
                float v[8];
                ldh8(B + (size_t)s * HIDDEN + p * 8, v);
                #pragma unroll
                for (int k = 0; k < 8; ++k) h[k] += v[k];
            }
            #pragma unroll
            for (int k = 0; k < 8; ++k) h[k] = fmaxf(h[k] + bv[k], 0.f);
        }
        int gf = __builtin_amdgcn_readfirstlane(g);
        bool uniform = (__ballot(g == gf) == ~0ull);
        if (uniform) {
            // reduce the 32 node-groups of this wave (lane strides 2..32)
            #pragma unroll
            for (int m = 2; m <= 32; m <<= 1) {
                #pragma unroll
                for (int k = 0; k < 8; ++k) h[k] += __shfl_xor(h[k], m, 64);
            }
            if (lane < 2) {
                float* sp = &ssum[gf * HIDDEN + lane * 8];
                #pragma unroll
                for (int k = 0; k < 8; ++k) atomicAdd(sp + k, h[k]);
            }
            if (lane == 0) {
                int wfirst = nb + ((t >> 6) << 5);
                int cnt = min(32, n1 - wfirst);
                if (cnt > 0) atomicAdd(&scnt[gf], (float)cnt);
            }
        } else if (active) {
            float* sp = &ssum[g * HIDDEN + p * 8];
            #pragma unroll
            for (int k = 0; k < 8; ++k) atomicAdd(sp + k, h[k]);
            if (p == 0) atomicAdd(&scnt[g], 1.f);
        }
    }
    __syncthreads();
    // flush block partials (device-scope atomics; memory-side on gfx950)
    for (int i = t; i < NUM_GRAPHS * HIDDEN; i += 256) {
        float v = ssum[i];
        if (v != 0.f) atomicAdd(&sums[i], v);
    }
    if (t < NUM_GRAPHS) {
        float v = scnt[t];
        if (v != 0.f) atomicAdd(&counts[t], v);
    }
    __syncthreads();   // drain this block's flush before signaling done
    if (t == 0) sdone = atomicAdd(done, 1u);
    __syncthreads();
    if (sdone == POOL_BLOCKS - 1) {
        // last block: all other blocks' flushes complete -> FC head (validated)
        __threadfence();
        for (int i = t; i < NUM_GRAPHS * NUM_CLS; i += 256) {
            int g = i / NUM_CLS, c = i % NUM_CLS;
            float inv = 1.0f / fmaxf(counts[g], 1.0f);
            float acc = bfc[c];
            #pragma unroll
            for (int kk = 0; kk < HIDDEN; ++kk)
                acc += (sums[g * HIDDEN + kk] * inv) * Wfc[kk * NUM_CLS + c];
            out[i] = acc;
        }
    }
}

extern "C" void kernel_launch(void* const* d_in, const int* in_sizes, int n_in,
                              void* d_out, int out_size, void* d_ws, size_t ws_size,
                              hipStream_t stream) {
    const float* x    = (const float*)d_in[0];
    const int*   ei   = (const int*)d_in[1];   // [2, E] (src row then dst row)
    const int*   batch= (const int*)d_in[2];
    const float* W1   = (const float*)d_in[3];
    const float* b1   = (const float*)d_in[4];
    const float* W2   = (const float*)d_in[5];
    const float* b2   = (const float*)d_in[6];
    const float* Wfc  = (const float*)d_in[7];
    const float* bfc  = (const float*)d_in[8];
    float* out = (float*)d_out;

    const size_t NB = (size_t)N_NODES * HIDDEN * sizeof(__half);   // 3.2 MB
    char* ws = (char*)d_ws;
    size_t off = 0;
    __half* A = (__half*)(ws + off); off += NB;
    __half* B = (__half*)(ws + off); off += NB;
    // zero-area (contiguous): sums | counts | done — zeroed by k_bscan block 0
    float*    sums   = (float*)(ws + off);    off += (size_t)NUM_GRAPHS * HIDDEN * sizeof(float);
    float*    counts = (float*)(ws + off);    off += (size_t)NUM_GRAPHS * sizeof(float);
    unsigned* done   = (unsigned*)(ws + off); off += 16;
    const int nz = NUM_GRAPHS * HIDDEN + NUM_GRAPHS + 4;
    int* row  = (int*)(ws + off); off += (size_t)(N_NODES + 4) * sizeof(int);
    int* cnt  = (int*)(ws + off); off += (size_t)NBUCK * NBLK * sizeof(int);
    int* btot = (int*)(ws + off); off += (size_t)NBUCK * sizeof(int);
    off = (off + 15) & ~(size_t)15;
    int* srcidx = (int*)(ws + off); off += (size_t)N_EDGES * sizeof(int);
    // packed edge words alias B (2.56 MB <= 3.2 MB): place writes / build reads
    // strictly before k_g1f (stream-ordered) overwrites B.
    unsigned* packed = (unsigned*)B;

    const int gridG1  = (N_NODES + 127) / 128;
    const int poolChunk = (N_NODES + POOL_BLOCKS - 1) / POOL_BLOCKS;

    // K1: mm1 || bucket histogram (R5-proven overlap)
    k_mm1_bcount<<<GRID_MM1 + NBLK, 256, 0, stream>>>(x, W1, A, ei, cnt);
    // K2: per-bucket scan (+ zero sums/counts/done)
    k_bscan<<<NBUCK, 256, 0, stream>>>(cnt, btot, (int*)sums, nz);
    // K3: place edges into contiguous bucket regions
    k_place<<<NBLK, 256, 0, stream>>>(ei, cnt, btot, packed);
    // K4: per-bucket CSR finalize (contiguous srcidx, row sentinel)
    k_build<<<NBUCK, 256, 0, stream>>>(packed, btot, row, srcidx);
    // K5: layer 1+2 fused: B = relu(A + gather(A) + b1) @ W2
    k_g1f<<<gridG1, 256, 0, stream>>>(row, srcidx, A, b1, W2, B, N_NODES);
    // K6: pool(relu(B + gather(B) + b2)) -> sums/counts ; last block does FC
    k_g2p<<<POOL_BLOCKS, 256, 0, stream>>>(row, srcidx, B, b2, batch, sums, counts,
                                           done, Wfc, bfc, out, N_NODES, poolChunk);
}